// Round 1
// baseline (96943.005 us; speedup 1.0000x reference)
//
#include <hip/hip_runtime.h>

// ---------------------------------------------------------------------------
// LSTM LM sampling loop, 128 sequential steps, persistent cooperative-style
// kernel with hand-rolled grid barriers.
//
// Exact-match strategy for jax.random.categorical:
//   JAX partitionable threefry (default since jax 0.4.36):
//     key_t      = threefry2x32((0,42), (0, t))           (fold-like split)
//     bits(b,v)  = y0 ^ y1 of threefry2x32(key_t, (0, b*V+v))
//     u          = max(bitcast(bits>>9 | 0x3f800000) - 1, tiny)
//     gumbel     = -log(-log(u));  idx = argmax(logits + gumbel), first-idx ties
//   Legacy path kept behind JAX_PARTITIONABLE=0 in case env runs old JAX.
// ---------------------------------------------------------------------------

#define JAX_PARTITIONABLE 1

#define B_   32
#define E_   128
#define H_   128
#define V_   50257
#define T_   128
#define NB_  786           // grid blocks; 64 logit columns each; 786*64=50304
#define NPAD_ 50304
#define TINY_ 1.17549435e-38f

typedef unsigned int u32;
typedef unsigned long long u64;

__device__ __forceinline__ void tf2x32(u32 k0, u32 k1, u32 x0, u32 x1,
                                       u32& o0, u32& o1) {
  u32 k2 = k0 ^ k1 ^ 0x1BD11BDAu;
  x0 += k0; x1 += k1;
#define RND_(r) { x0 += x1; x1 = ((x1 << (r)) | (x1 >> (32 - (r)))); x1 ^= x0; }
  RND_(13) RND_(15) RND_(26) RND_(6)
  x0 += k1; x1 += k2 + 1u;
  RND_(17) RND_(29) RND_(16) RND_(24)
  x0 += k2; x1 += k0 + 2u;
  RND_(13) RND_(15) RND_(26) RND_(6)
  x0 += k0; x1 += k1 + 3u;
  RND_(17) RND_(29) RND_(16) RND_(24)
  x0 += k1; x1 += k2 + 4u;
  RND_(13) RND_(15) RND_(26) RND_(6)
  x0 += k2; x1 += k0 + 5u;
#undef RND_
  o0 = x0; o1 = x1;
}

__device__ __forceinline__ float sigm_(float x) { return 1.0f / (1.0f + expf(-x)); }

// 2-level grid barrier: 16 sprayed arrival counters (64B apart) -> 1 global
// counter -> 16 sprayed release flags. Monotonic phase ids, memset-0 init.
__device__ __forceinline__ void grid_barrier(u32* bar, u32 phase) {
  __syncthreads();
  if (threadIdx.x == 0) {
    __threadfence();
    const u32 slot = blockIdx.x & 15u;
    const u32 cnt  = (NB_ + 15u - slot) >> 4;   // #blocks with blockIdx%16==slot
    u32 a = __hip_atomic_fetch_add(bar + slot * 16, 1u,
                                   __ATOMIC_ACQ_REL, __HIP_MEMORY_SCOPE_AGENT) + 1u;
    if (a == phase * cnt) {
      u32 g = __hip_atomic_fetch_add(bar + 256, 1u,
                                     __ATOMIC_ACQ_REL, __HIP_MEMORY_SCOPE_AGENT) + 1u;
      if (g == phase * 16u) {
#pragma unroll
        for (int i = 0; i < 16; ++i)
          __hip_atomic_store(bar + 272 + i * 16, phase,
                             __ATOMIC_RELEASE, __HIP_MEMORY_SCOPE_AGENT);
      }
    }
    while (__hip_atomic_load(bar + 272 + slot * 16,
                             __ATOMIC_ACQUIRE, __HIP_MEMORY_SCOPE_AGENT) < phase)
      __builtin_amdgcn_s_sleep(1);
    __threadfence();
  }
  __syncthreads();
}

// One-time W_lin transpose into [kc][col][4] (float4 per (kc,col)), zero-padded.
__global__ void transpose_w(const float* __restrict__ W, float4* __restrict__ Wt) {
  int id = blockIdx.x * 256 + threadIdx.x;          // over 32 * NPAD_
  if (id >= 32 * NPAD_) return;
  int kc = id / NPAD_;
  int c  = id - kc * NPAD_;
  float4 v = make_float4(0.f, 0.f, 0.f, 0.f);
  if (c < V_) v = *(const float4*)(W + (size_t)c * H_ + kc * 4);
  Wt[id] = v;
}

__global__ void __launch_bounds__(256, 4) lstm_main(
    const float* __restrict__ x_in, const float* __restrict__ emb,
    const float* __restrict__ W_ih, const float* __restrict__ W_hh,
    const float* __restrict__ b_ih, const float* __restrict__ b_hh,
    const float* __restrict__ W_lin, const float* __restrict__ b_lin,
    float* __restrict__ out,
    float* S_spray, u64* G_spray, float* S_final,
    float* h_bk, float* c_ws, u32* bar, const float4* Wt) {

  const int tid  = threadIdx.x;
  const int lane = tid & 63;
  const int wav  = tid >> 6;            // wave 0..3, owns batch rows wav*8..wav*8+7
  const int blk  = blockIdx.x;
  const int c    = blk * 64 + lane;     // logit column
  const bool cva = (c < V_);
  const u32 spray = (u32)(blk & 15);

  __shared__ float cW_ih[16][128];      // cell blocks only: W_ih slice
  __shared__ float cW_hh[16][128];
  __shared__ float gl[4][4][32];        // gate exchange [gate][unit][b]

  if (blk < 32) {
    for (int i = tid; i < 16 * 128; i += 256) {
      const int rr = i >> 7, k = i & 127;
      const int q = rr >> 2, jl = rr & 3;
      cW_ih[rr][k] = W_ih[(q * 128 + blk * 4 + jl) * 128 + k];
      cW_hh[rr][k] = W_hh[(q * 128 + blk * 4 + jl) * 128 + k];
    }
  }
  __syncthreads();

  const float blin = cva ? b_lin[c] : 0.0f;
  float e_prev[8];                      // exp(logits) of previous step (own col/rows)
  u32 phase = 0;

  for (int t = 0; t < T_; ++t) {
    // ------------------ phase C: merge(t-1) + LSTM cell -> h_t ------------------
    if (blk < 32) {
      const int g  = blk;
      const int b  = tid & 31;
      const int q  = (tid >> 5) & 3;
      const int u2 = tid >> 7;
      if (tid == 0 && t > 0) {
        float s = 0.0f;
#pragma unroll
        for (int i = 0; i < 16; ++i) s += S_spray[((t - 1) * 32 + g) * 16 + i];
        S_final[(t - 1) * 32 + g] = s;
      }
      const float* xs;
      if (t == 0) {
        xs = x_in + b * E_;
      } else {
        u64 m = 0ull;
#pragma unroll
        for (int i = 0; i < 16; ++i) {
          u64 v = G_spray[((t - 1) * 32 + b) * 16 + i];
          m = m > v ? m : v;
        }
        const u32 idx = ~(u32)m;        // low 32 bits stored as ~col
        xs = emb + (size_t)idx * E_;
      }
      const float* hp = h_bk + ((t + 1) & 1) * (B_ * H_) + b * H_;
      float a2[2];
#pragma unroll
      for (int jj = 0; jj < 2; ++jj) {
        const int jl = u2 * 2 + jj;
        const int rr = q * 4 + jl;
        const int grow = q * 128 + g * 4 + jl;
        float a = b_ih[grow] + b_hh[grow];
#pragma unroll 4
        for (int kc = 0; kc < 32; ++kc) {
          float4 xv = *(const float4*)(xs + kc * 4);
          float4 wv = *(const float4*)(&cW_ih[rr][kc * 4]);
          float4 hv = *(const float4*)(hp + kc * 4);
          float4 wh = *(const float4*)(&cW_hh[rr][kc * 4]);
          a = fmaf(xv.x, wv.x, a); a = fmaf(xv.y, wv.y, a);
          a = fmaf(xv.z, wv.z, a); a = fmaf(xv.w, wv.w, a);
          a = fmaf(hv.x, wh.x, a); a = fmaf(hv.y, wh.y, a);
          a = fmaf(hv.z, wh.z, a); a = fmaf(hv.w, wh.w, a);
        }
        a2[jj] = a;
      }
      gl[q][u2 * 2 + 0][b] = a2[0];
      gl[q][u2 * 2 + 1][b] = a2[1];
      __syncthreads();
      if (tid < 128) {
        const int b2 = tid & 31;
        const int jl = (tid >> 5) & 3;
        const float iv = gl[0][jl][b2];
        const float fv = gl[1][jl][b2];
        const float gv = gl[2][jl][b2];
        const float ov = gl[3][jl][b2];
        const int j = g * 4 + jl;
        const float cold = c_ws[b2 * H_ + j];
        const float cn = sigm_(fv) * cold + sigm_(iv) * tanhf(gv);
        const float hn = sigm_(ov) * tanhf(cn);
        c_ws[b2 * H_ + j] = cn;
        h_bk[(t & 1) * (B_ * H_) + b2 * H_ + j] = hn;
      }
    }
    phase += 1; grid_barrier(bar, phase);

    // ------------------ phase X: probs(t-1) write + logits(t) ------------------
    if (t > 0) {
#pragma unroll
      for (int r = 0; r < 8; ++r) {
        const int b = wav * 8 + r;
        const float sfin = S_final[(t - 1) * 32 + b];
        if (cva) {
          float p = e_prev[r] * (1.0f / sfin);
          __builtin_nontemporal_store(p, out + ((size_t)b * T_ + (t - 1)) * V_ + c);
        }
      }
    }

    float acc[8];
#pragma unroll
    for (int r = 0; r < 8; ++r) acc[r] = blin;
    {
      const float* hb = h_bk + (t & 1) * (B_ * H_);
      if (Wt) {
#pragma unroll 8
        for (int kc = 0; kc < 32; ++kc) {
          float4 w4 = Wt[kc * NPAD_ + c];
#pragma unroll
          for (int r = 0; r < 8; ++r) {
            float4 h4 = *(const float4*)(hb + (wav * 8 + r) * H_ + kc * 4);
            acc[r] = fmaf(w4.x, h4.x, acc[r]);
            acc[r] = fmaf(w4.y, h4.y, acc[r]);
            acc[r] = fmaf(w4.z, h4.z, acc[r]);
            acc[r] = fmaf(w4.w, h4.w, acc[r]);
          }
        }
      } else {
        const int cc = cva ? c : (V_ - 1);
        const float* wp = W_lin + (size_t)cc * H_;
#pragma unroll 8
        for (int kc = 0; kc < 32; ++kc) {
          float4 w4 = *(const float4*)(wp + kc * 4);
#pragma unroll
          for (int r = 0; r < 8; ++r) {
            float4 h4 = *(const float4*)(hb + (wav * 8 + r) * H_ + kc * 4);
            acc[r] = fmaf(w4.x, h4.x, acc[r]);
            acc[r] = fmaf(w4.y, h4.y, acc[r]);
            acc[r] = fmaf(w4.z, h4.z, acc[r]);
            acc[r] = fmaf(w4.w, h4.w, acc[r]);
          }
        }
      }
    }

    // step key
    u32 k1t, k2t;
#if JAX_PARTITIONABLE
    tf2x32(0u, 42u, 0u, (u32)t, k1t, k2t);
#else
    {
      u32 i0 = 2u * (u32)t, i1 = 2u * (u32)t + 1u, junk;
      if (i0 < 128u) { tf2x32(0u, 42u, i0, i0 + 128u, k1t, junk); }
      else           { tf2x32(0u, 42u, i0 - 128u, i0, junk, k1t); }
      if (i1 < 128u) { tf2x32(0u, 42u, i1, i1 + 128u, k2t, junk); }
      else           { tf2x32(0u, 42u, i1 - 128u, i1, junk, k2t); }
    }
#endif

#pragma unroll
    for (int r = 0; r < 8; ++r) {
      const int b = wav * 8 + r;
      const float l = acc[r];
      float e = 0.0f;
      u64 pk = 0ull;
      if (cva) {
        e = expf(l);
        u32 y0, y1, bits;
#if JAX_PARTITIONABLE
        tf2x32(k1t, k2t, 0u, (u32)(b * V_ + c), y0, y1);
        bits = y0 ^ y1;
#else
        {
          u32 j = (u32)((b & 15) * V_ + c);
          tf2x32(k1t, k2t, j, j + 16u * (u32)V_, y0, y1);
          bits = (b < 16) ? y0 : y1;
        }
#endif
        float f = __uint_as_float((bits >> 9) | 0x3f800000u) - 1.0f;
        float u = fmaxf(f + TINY_, TINY_);
        float gmb = -logf(-logf(u));
        float val = l + gmb;
        u32 sv = __float_as_uint(val);
        sv ^= (sv & 0x80000000u) ? 0xFFFFFFFFu : 0x80000000u;  // monotone sortable
        pk = ((u64)sv << 32) | (u64)(u32)(~(u32)c);            // first-idx tiebreak
      }
      float s = e;
#pragma unroll
      for (int m = 32; m >= 1; m >>= 1) s += __shfl_xor(s, m, 64);
#pragma unroll
      for (int m = 32; m >= 1; m >>= 1) {
        u64 o = __shfl_xor(pk, m, 64);
        pk = pk > o ? pk : o;
      }
      if (lane == 0) {
        atomicAdd(S_spray + ((t * 32 + b) * 16) + spray, s);
        atomicMax(G_spray + ((t * 32 + b) * 16) + spray, pk);
      }
      e_prev[r] = e;
    }
    phase += 1; grid_barrier(bar, phase);
  }

  // ------------------ tail: finalize probs for t = T-1 ------------------
  if (blk < 32 && tid == 0) {
    float s = 0.0f;
#pragma unroll
    for (int i = 0; i < 16; ++i) s += S_spray[((T_ - 1) * 32 + blk) * 16 + i];
    S_final[(T_ - 1) * 32 + blk] = s;
  }
  phase += 1; grid_barrier(bar, phase);
#pragma unroll
  for (int r = 0; r < 8; ++r) {
    const int b = wav * 8 + r;
    const float sfin = S_final[(T_ - 1) * 32 + b];
    if (cva) {
      float p = e_prev[r] * (1.0f / sfin);
      __builtin_nontemporal_store(p, out + ((size_t)b * T_ + (T_ - 1)) * V_ + c);
    }
  }
}

extern "C" void kernel_launch(void* const* d_in, const int* in_sizes, int n_in,
                              void* d_out, int out_size, void* d_ws, size_t ws_size,
                              hipStream_t stream) {
  const float* x_in  = (const float*)d_in[0];
  // d_in[1] = max_seq_length (int, ==128) — compile-time constant here
  const float* emb   = (const float*)d_in[2];
  const float* W_ih  = (const float*)d_in[3];
  const float* W_hh  = (const float*)d_in[4];
  const float* b_ih  = (const float*)d_in[5];
  const float* b_hh  = (const float*)d_in[6];
  const float* W_lin = (const float*)d_in[7];
  const float* b_lin = (const float*)d_in[8];
  float* out = (float*)d_out;

  char* ws = (char*)d_ws;
  float* S_spray = (float*)(ws + 0);                    // 128*32*16 f32 = 256KB
  u64*   G_spray = (u64*)(ws + (256 << 10));            // 128*32*16 u64 = 512KB
  float* S_final = (float*)(ws + (768 << 10));          // 128*32 f32   = 16KB
  float* h_bk    = (float*)(ws + (784 << 10));          // 2*32*128 f32 = 32KB
  float* c_ws    = (float*)(ws + (816 << 10));          // 32*128 f32   = 16KB
  u32*   bar     = (u32*)(ws + (832 << 10));            // 4KB barrier state
  float4* Wt     = (float4*)(ws + (1 << 20));           // 32*50304 float4 ~ 25.8MB

  const size_t wt_bytes = (size_t)32 * NPAD_ * sizeof(float4);
  const bool useWt = ws_size >= (size_t)(1 << 20) + wt_bytes;

  // zero control/state region (sprays, finals, h/c, barrier)
  hipMemsetAsync(d_ws, 0, (size_t)(1 << 20) < ws_size ? (size_t)(1 << 20) : ws_size,
                 stream);

  if (useWt) {
    const int total = 32 * NPAD_;
    transpose_w<<<(total + 255) / 256, 256, 0, stream>>>(W_lin, Wt);
  }

  lstm_main<<<NB_, 256, 0, stream>>>(x_in, emb, W_ih, W_hh, b_ih, b_hh,
                                     W_lin, b_lin, out,
                                     S_spray, G_spray, S_final, h_bk, c_ws, bar,
                                     useWt ? Wt : (const float4*)nullptr);
}